// Round 4
// baseline (503.429 us; speedup 1.0000x reference)
//
#include <hip/hip_runtime.h>
#include <hip/hip_bf16.h>

#define SEQ 2048
#define HID 2048
#define NB  8
#define WMAX 30
#define EPSF 1e-8f
#define ENC_NEGINF 0x007fffffu
#define NSEG ((size_t)NB * SEQ)

// ws layout (floats): [0] dot1 | [1] dot2 | [2] nsq | then NB uint counters.

// order-preserving uint encoding of float (no NaNs present)
__device__ __forceinline__ unsigned enc_f(float f) {
    unsigned u = __float_as_uint(f);
    return (u & 0x80000000u) ? ~u : (u | 0x80000000u);
}
__device__ __forceinline__ float dec_f(unsigned k) {
    unsigned u = (k & 0x80000000u) ? (k ^ 0x80000000u) : ~k;
    return __uint_as_float(u);
}

// Single fused kernel. Grid = NB*SEQ/8 = 2048 blocks x 512 threads.
// Phase A (every block): 8 waves, 1 row/wave -> dot1, dot2, nsq into ws.
// Then threadfence + atomicAdd(cnt[b]); the 256th finisher per example runs
// Phase B: band argmax + LDS scatter-max + stats + flip + output.
__global__ __launch_bounds__(512)
void fused_all(const float* __restrict__ seq, const int* __restrict__ idxs,
               float* __restrict__ ws, unsigned* __restrict__ cnt,
               float* __restrict__ out) {
    __shared__ float d2s[SEQ];
    __shared__ float nss[SEQ];
    __shared__ unsigned evs[SEQ];
    __shared__ float red[5][8];
    __shared__ int last;

    int bid = blockIdx.x;
    int b = bid >> 8;                 // 256 blocks per example
    int rbase = (bid & 255) * 8;
    int t = threadIdx.x;
    int w = t >> 6, lane = t & 63;

    int sep0 = idxs[2 * b], sep1 = idxs[2 * b + 1];

    // ---------------- Phase A: streaming dots ----------------
    const float4* q1p = (const float4*)(seq + ((size_t)b * SEQ + 1) * HID);
    const float4* q2p = (const float4*)(seq + ((size_t)b * SEQ + (sep0 - 1)) * HID);

    float4 q1r[8], q2r[8];
#pragma unroll
    for (int k = 0; k < 8; ++k) {
        q1r[k] = q1p[k * 64 + lane];
        q2r[k] = q2p[k * 64 + lane];
    }

    int i = rbase + w;
    const float4* rp = (const float4*)(seq + ((size_t)b * SEQ + i) * HID);

    float s1 = 0.f, s2 = 0.f, s3 = 0.f;
#pragma unroll
    for (int k = 0; k < 8; ++k) {
        float4 v = rp[k * 64 + lane];
        s1 += v.x * q1r[k].x + v.y * q1r[k].y + v.z * q1r[k].z + v.w * q1r[k].w;
        s2 += v.x * q2r[k].x + v.y * q2r[k].y + v.z * q2r[k].z + v.w * q2r[k].w;
        s3 += v.x * v.x      + v.y * v.y      + v.z * v.z      + v.w * v.w;
    }
#pragma unroll
    for (int off = 32; off; off >>= 1) {
        s1 += __shfl_xor(s1, off);
        s2 += __shfl_xor(s2, off);
        s3 += __shfl_xor(s3, off);
    }
    if (lane == 0) {
        size_t o = (size_t)b * SEQ + i;
        ws[o] = s1;
        ws[NSEG + o] = s2;
        ws[2 * NSEG + o] = s3;
    }

    // ---------------- handoff: last block per example continues ----------------
    __threadfence();                       // release our ws writes (device scope)
    if (t == 0) {
        unsigned old = atomicAdd(&cnt[b], 1u);
        last = (old == 255u);
    }
    __syncthreads();
    if (!last) return;
    __threadfence();                       // acquire other blocks' ws writes

    // ---------------- Phase B: band + scatter-max + stats ----------------
    const float* dot1 = ws + (size_t)b * SEQ;
    const float* dot2 = ws + NSEG + (size_t)b * SEQ;
    const float* nsq  = ws + 2 * NSEG + (size_t)b * SEQ;

#pragma unroll
    for (int r = 0; r < 4; ++r) {
        int ii = t + r * 512;
        d2s[ii] = dot2[ii];
        nss[ii] = nsq[ii];
        evs[ii] = ENC_NEGINF;
    }
    __syncthreads();

    float invq = 1.0f / fmaxf(sqrtf(nss[1] + nss[sep0 - 1]), EPSF);

    float slog[4];
#pragma unroll
    for (int r = 0; r < 4; ++r) {
        int ii = t + r * 512;
        bool range_ok = (ii >= sep0 + 1) && (ii < sep1);
        float d1 = dot1[ii];
        float ni = nss[ii];
        float best = -__builtin_inff();
        int arg = 0;
        bool any = false;
#pragma unroll
        for (int d = 0; d < WMAX; ++d) {
            int jraw = ii + d;
            if (range_ok && jraw < sep1) {   // valid => jraw <= 2045, safe index
                float num = d1 + d2s[jraw];
                float sim = num * rsqrtf(ni + nss[jraw]) * invq;
                if (sim > best) { best = sim; arg = d; }
                any = true;
            }
        }
        slog[r] = any ? best : 0.0f;
        if (any) {
            int e = ii + arg;
            if (e > SEQ - 1) e = SEQ - 1;
            atomicMax(&evs[e], enc_f(best));
        }
    }
    __syncthreads();

    float elog[4];
#pragma unroll
    for (int r = 0; r < 4; ++r) {
        int ii = t + r * 512;
        unsigned k = evs[ii];
        elog[r] = (k == ENC_NEGINF) ? 0.0f : dec_f(k);
    }

    float ssum = 0.f, ssq = 0.f, esum = 0.f, esq = 0.f, smax = -__builtin_inff();
#pragma unroll
    for (int r = 0; r < 4; ++r) {
        ssum += slog[r]; ssq += slog[r] * slog[r];
        esum += elog[r]; esq += elog[r] * elog[r];
        smax = fmaxf(smax, slog[r]);
    }
#pragma unroll
    for (int off = 32; off; off >>= 1) {
        ssum += __shfl_xor(ssum, off);
        ssq  += __shfl_xor(ssq,  off);
        esum += __shfl_xor(esum, off);
        esq  += __shfl_xor(esq,  off);
        smax = fmaxf(smax, __shfl_xor(smax, off));
    }
    if (lane == 0) {
        red[0][w] = ssum; red[1][w] = ssq; red[2][w] = esum;
        red[3][w] = esq;  red[4][w] = smax;
    }
    __syncthreads();

    float S0 = 0.f, S1 = 0.f, E0 = 0.f, E1 = 0.f, MX = -__builtin_inff();
#pragma unroll
    for (int k = 0; k < 8; ++k) {
        S0 += red[0][k]; S1 += red[1][k]; E0 += red[2][k];
        E1 += red[3][k]; MX = fmaxf(MX, red[4][k]);
    }
    float ms = S0 / SEQ;
    float ss = sqrtf(fmaxf(S1 - SEQ * ms * ms, 0.f) / (SEQ - 1));
    float me = E0 / SEQ;
    float se = sqrtf(fmaxf(E1 - SEQ * me * me, 0.f) / (SEQ - 1));
    bool flip = (MX < ms + ss) || (MX < me + se);

#pragma unroll
    for (int r = 0; r < 4; ++r) {
        int ii = t + r * 512;
        float so = slog[r], eo = elog[r];
        if (flip) {
            so = (so == 0.f) ? -0.001f : -so;
            eo = (eo == 0.f) ? -0.001f : -eo;
        }
        out[(size_t)b * SEQ + ii] = so;
        out[NSEG + (size_t)b * SEQ + ii] = eo;
    }
}

extern "C" void kernel_launch(void* const* d_in, const int* in_sizes, int n_in,
                              void* d_out, int out_size, void* d_ws, size_t ws_size,
                              hipStream_t stream) {
    const float* seq = (const float*)d_in[0];
    const int* idxs = (const int*)d_in[1];
    float* out = (float*)d_out;
    float* ws = (float*)d_ws;
    unsigned* cnt = (unsigned*)((char*)d_ws + 3 * NSEG * sizeof(float));

    // counters must be zero at kernel start on EVERY call (graph replays do
    // not re-poison) -- memset is graph-capturable.
    hipMemsetAsync(cnt, 0, NB * sizeof(unsigned), stream);
    fused_all<<<NB * SEQ / 8, 512, 0, stream>>>(seq, idxs, ws, cnt, out);
}

// Round 5
// 33.278 us; speedup vs baseline: 15.1281x; 15.1281x over previous
//
#include <hip/hip_runtime.h>
#include <hip/hip_bf16.h>

#define SEQ 2048
#define HID 2048
#define NB  8
#define WMAX 30
#define EPSF 1e-8f
#define ENC_NEGINF 0x007fffffu
#define NSEG ((size_t)NB * SEQ)

// ws layout (floats): [0] dot1 | [1] dot2 | [2] nsq  (each NB*SEQ)

// ---------------- Kernel 1: per-row dot1, dot2, nsq ----------------
// 512 threads = 8 waves, 1 row per wave. Grid = NB*SEQ/8 = 2048 blocks.
// Only rows {1} U [sep0-1, sep1) are ever consumed downstream -> blocks
// whose 8-row slab is fully outside that set exit before loading anything.
__global__ __launch_bounds__(512)
void k1_dots(const float* __restrict__ seq, const int* __restrict__ idxs,
             float* __restrict__ ws) {
    int bid = blockIdx.x;
    int b = bid >> 8;                 // 256 blocks per example
    int rbase = (bid & 255) * 8;
    int t = threadIdx.x;
    int w = t >> 6, lane = t & 63;

    int sep0 = idxs[2 * b], sep1 = idxs[2 * b + 1];

    // needed rows: {1} U [sep0-1, sep1)
    bool needed = (rbase == 0) || (rbase + 8 > sep0 - 1 && rbase < sep1);
    if (!needed) return;

    const float4* q1p = (const float4*)(seq + ((size_t)b * SEQ + 1) * HID);
    const float4* q2p = (const float4*)(seq + ((size_t)b * SEQ + (sep0 - 1)) * HID);

    float4 q1r[8], q2r[8];
#pragma unroll
    for (int k = 0; k < 8; ++k) {
        q1r[k] = q1p[k * 64 + lane];
        q2r[k] = q2p[k * 64 + lane];
    }

    int i = rbase + w;
    const float4* rp = (const float4*)(seq + ((size_t)b * SEQ + i) * HID);

    float s1 = 0.f, s2 = 0.f, s3 = 0.f;
#pragma unroll
    for (int k = 0; k < 8; ++k) {
        float4 v = rp[k * 64 + lane];
        s1 += v.x * q1r[k].x + v.y * q1r[k].y + v.z * q1r[k].z + v.w * q1r[k].w;
        s2 += v.x * q2r[k].x + v.y * q2r[k].y + v.z * q2r[k].z + v.w * q2r[k].w;
        s3 += v.x * v.x      + v.y * v.y      + v.z * v.z      + v.w * v.w;
    }
#pragma unroll
    for (int off = 32; off; off >>= 1) {
        s1 += __shfl_xor(s1, off);
        s2 += __shfl_xor(s2, off);
        s3 += __shfl_xor(s3, off);
    }
    if (lane == 0) {
        size_t o = (size_t)b * SEQ + i;
        ws[o] = s1;
        ws[NSEG + o] = s2;
        ws[2 * NSEG + o] = s3;
    }
}

// order-preserving uint encoding of float (no NaNs present)
__device__ __forceinline__ unsigned enc_f(float f) {
    unsigned u = __float_as_uint(f);
    return (u & 0x80000000u) ? ~u : (u | 0x80000000u);
}
__device__ __forceinline__ float dec_f(unsigned k) {
    unsigned u = (k & 0x80000000u) ? (k ^ 0x80000000u) : ~k;
    return __uint_as_float(u);
}

// ---------------- Kernel 2: band + scatter-max + stats + flip + out ----------------
// One block per example, 1024 threads, 2 rows/thread. Everything in LDS.
__global__ __launch_bounds__(1024)
void k2_all(const float* __restrict__ ws, const int* __restrict__ idxs,
            float* __restrict__ out) {
    __shared__ float d2s[SEQ];
    __shared__ float nss[SEQ];
    __shared__ unsigned evs[SEQ];
    __shared__ float red[5][16];

    int b = blockIdx.x;
    int t = threadIdx.x;
    int sep0 = idxs[2 * b], sep1 = idxs[2 * b + 1];

    const float* dot1 = ws + (size_t)b * SEQ;
    const float* dot2 = ws + NSEG + (size_t)b * SEQ;
    const float* nsq  = ws + 2 * NSEG + (size_t)b * SEQ;

#pragma unroll
    for (int r = 0; r < 2; ++r) {
        int ii = t + r * 1024;
        d2s[ii] = dot2[ii];
        nss[ii] = nsq[ii];
        evs[ii] = ENC_NEGINF;
    }
    __syncthreads();

    float invq = 1.0f / fmaxf(sqrtf(nss[1] + nss[sep0 - 1]), EPSF);

    float slog[2];
#pragma unroll
    for (int r = 0; r < 2; ++r) {
        int ii = t + r * 1024;
        bool range_ok = (ii >= sep0 + 1) && (ii < sep1);
        float d1 = dot1[ii];
        float ni = nss[ii];
        float best = -__builtin_inff();
        int arg = 0;
        bool any = false;
#pragma unroll
        for (int d = 0; d < WMAX; ++d) {
            int jraw = ii + d;
            if (range_ok && jraw < sep1) {   // valid => jraw <= 2045, in-bounds
                float num = d1 + d2s[jraw];
                float sim = num * rsqrtf(ni + nss[jraw]) * invq;
                if (sim > best) { best = sim; arg = d; }
                any = true;
            }
        }
        slog[r] = any ? best : 0.0f;
        if (any) {
            int e = ii + arg;
            if (e > SEQ - 1) e = SEQ - 1;
            atomicMax(&evs[e], enc_f(best));
        }
    }
    __syncthreads();

    float elog[2];
#pragma unroll
    for (int r = 0; r < 2; ++r) {
        int ii = t + r * 1024;
        unsigned k = evs[ii];
        elog[r] = (k == ENC_NEGINF) ? 0.0f : dec_f(k);
    }

    float ssum = 0.f, ssq = 0.f, esum = 0.f, esq = 0.f, smax = -__builtin_inff();
#pragma unroll
    for (int r = 0; r < 2; ++r) {
        ssum += slog[r]; ssq += slog[r] * slog[r];
        esum += elog[r]; esq += elog[r] * elog[r];
        smax = fmaxf(smax, slog[r]);
    }
#pragma unroll
    for (int off = 32; off; off >>= 1) {
        ssum += __shfl_xor(ssum, off);
        ssq  += __shfl_xor(ssq,  off);
        esum += __shfl_xor(esum, off);
        esq  += __shfl_xor(esq,  off);
        smax = fmaxf(smax, __shfl_xor(smax, off));
    }
    int lane = t & 63, w = t >> 6;
    if (lane == 0) {
        red[0][w] = ssum; red[1][w] = ssq; red[2][w] = esum;
        red[3][w] = esq;  red[4][w] = smax;
    }
    __syncthreads();

    float S0 = 0.f, S1 = 0.f, E0 = 0.f, E1 = 0.f, MX = -__builtin_inff();
#pragma unroll
    for (int k = 0; k < 16; ++k) {
        S0 += red[0][k]; S1 += red[1][k]; E0 += red[2][k];
        E1 += red[3][k]; MX = fmaxf(MX, red[4][k]);
    }
    float ms = S0 / SEQ;
    float ss = sqrtf(fmaxf(S1 - SEQ * ms * ms, 0.f) / (SEQ - 1));
    float me = E0 / SEQ;
    float se = sqrtf(fmaxf(E1 - SEQ * me * me, 0.f) / (SEQ - 1));
    bool flip = (MX < ms + ss) || (MX < me + se);

#pragma unroll
    for (int r = 0; r < 2; ++r) {
        int ii = t + r * 1024;
        float so = slog[r], eo = elog[r];
        if (flip) {
            so = (so == 0.f) ? -0.001f : -so;
            eo = (eo == 0.f) ? -0.001f : -eo;
        }
        out[(size_t)b * SEQ + ii] = so;
        out[NSEG + (size_t)b * SEQ + ii] = eo;
    }
}

extern "C" void kernel_launch(void* const* d_in, const int* in_sizes, int n_in,
                              void* d_out, int out_size, void* d_ws, size_t ws_size,
                              hipStream_t stream) {
    const float* seq = (const float*)d_in[0];
    const int* idxs = (const int*)d_in[1];
    float* out = (float*)d_out;
    float* ws = (float*)d_ws;

    k1_dots<<<NB * SEQ / 8, 512, 0, stream>>>(seq, idxs, ws);
    k2_all<<<NB, 1024, 0, stream>>>(ws, idxs, out);
}